// Round 6
// baseline (223.420 us; speedup 1.0000x reference)
//
#include <hip/hip_runtime.h>

#define B_    4
#define C_    192
#define N_    8192
#define K_    16
#define O_    192
#define TWOC_ 384
#define YPAD  392   // LDS row stride (shorts): 196 dwords = 4 mod 32 banks -> 2-way (free)
#define NB_   16    // nodes per fused block

typedef __attribute__((ext_vector_type(8))) short short8;
typedef __attribute__((ext_vector_type(4))) short short4v;
typedef __attribute__((ext_vector_type(2))) unsigned int uint2v;
typedef __attribute__((ext_vector_type(4))) float floatx4;

static __device__ __forceinline__ float bf_lo(unsigned int u) {
    union { unsigned int i; float f; } v; v.i = u << 16; return v.f;
}
static __device__ __forceinline__ float bf_hi(unsigned int u) {
    union { unsigned int i; float f; } v; v.i = u & 0xffff0000u; return v.f;
}
static __device__ __forceinline__ unsigned short f2bf(float f) {
    union { float f; unsigned int i; } v; v.f = f;
    unsigned int x = v.i;
    return (unsigned short)((x + 0x7FFFu + ((x >> 16) & 1u)) >> 16);
}

// ---------------- K0: transpose x[B,C,N] fp32 -> xt[B,N,192] bf16 ; tail = W->bf16 ----------------
__global__ __launch_bounds__(256) void k_prep(const float* __restrict__ x,
                                              const float* __restrict__ W,
                                              unsigned short* __restrict__ xt,
                                              unsigned short* __restrict__ Wb) {
    int bid = blockIdx.x;
    if (bid >= 6144) {                   // 288 tail blocks: W fp32 -> bf16
        int i = (bid - 6144) * 256 + threadIdx.x;
        if (i < O_ * TWOC_) Wb[i] = f2bf(W[i]);
        return;
    }
    __shared__ float tile[32][33];
    int xcd  = bid & 7;
    int b    = xcd >> 1;
    int half = xcd & 1;
    int slot = bid >> 3;                 // 0..767
    int ct   = slot >> 7;                // 0..5
    int nt   = half * 128 + (slot & 127);
    int c0 = ct * 32, n0 = nt * 32;
    int tid = threadIdx.x;

    int cc  = tid >> 3;
    int nn4 = (tid & 7) * 4;
    const float* xp = x + ((size_t)b * C_ + c0 + cc) * N_ + n0 + nn4;
    float4 v = *(const float4*)xp;
    tile[nn4 + 0][cc] = v.x;
    tile[nn4 + 1][cc] = v.y;
    tile[nn4 + 2][cc] = v.z;
    tile[nn4 + 3][cc] = v.w;
    __syncthreads();

#pragma unroll
    for (int i = 0; i < 2; i++) {
        int id  = i * 256 + tid;
        int row = id >> 4;
        int ch2 = id & 15;
        float a = tile[row][ch2 * 2];
        float c = tile[row][ch2 * 2 + 1];
        unsigned int pack = (unsigned int)f2bf(a) | ((unsigned int)f2bf(c) << 16);
        *(unsigned int*)(xt + ((size_t)b * N_ + n0 + row) * C_ + c0 + ch2 * 2) = pack;
    }
}

// ---------------- K1: fused max-rel gather + 1x1 conv, 16 nodes/block, 8 blocks/CU ----------------
__global__ __launch_bounds__(256, 8) void k_fused(const unsigned short* __restrict__ xt,
                                                  const int* __restrict__ eidx,
                                                  const unsigned short* __restrict__ Wb,
                                                  const float* __restrict__ bias,
                                                  float* __restrict__ out) {
    __shared__ unsigned short ytile[NB_][YPAD];   // 12.25 KiB
    __shared__ int sidx[NB_][36];                 // 2.25 KiB

    int bid  = blockIdx.x;               // 2048 blocks
    int xcd  = bid & 7;
    int b    = xcd >> 1;
    int slot = bid >> 3;                 // 0..255
    int n0   = ((xcd & 1) * 256 + slot) * NB_;

    int tid  = threadIdx.x;
    int wave = tid >> 6;
    int lane = tid & 63;

    // ---- edge indices: sidx[node][0..15]=j (e0), [16..31]=i (e1) ----
    {
        const int* e0 = eidx + ((size_t)b * N_ + n0) * K_;
        const int* e1 = e0 + (size_t)B_ * N_ * K_;
        int node = tid >> 4, k = tid & 15;   // 256 threads = 16 nodes x 16 k
        sidx[node][k]      = e0[tid];
        sidx[node][16 + k] = e1[tid];
    }

    // ---- stage A: own xs rows -> ytile[:, 0..191] (384 short8 chunks) ----
    {
        const unsigned short* xrow = xt + ((size_t)b * N_ + n0) * C_;
        int id = tid;                    // chunk 0..255
        {
            int row = id / 24, chunk = id % 24;
            short8 v = *(const short8*)(xrow + (size_t)row * C_ + chunk * 8);
            *(short8*)&ytile[row][chunk * 8] = v;
        }
        id = 256 + tid;
        if (id < 384) {
            int row = id / 24, chunk = id % 24;
            short8 v = *(const short8*)(xrow + (size_t)row * C_ + chunk * 8);
            *(short8*)&ytile[row][chunk * 8] = v;
        }
    }
    __syncthreads();

    // ---- stage B: gather max-rel -> ytile[:, 192..383] ----
    {
        int g  = lane >> 4;
        int l4 = lane & 15;
        int node = wave * 4 + g;         // 0..15
        const unsigned short* xbase = xt + (size_t)b * N_ * C_;

#define GLD(BUF, JN, IN)                                                    \
        {                                                                   \
            const unsigned short* pj = xbase + (size_t)(JN) * C_ + l4 * 4;  \
            const unsigned short* pi = xbase + (size_t)(IN) * C_ + l4 * 4;  \
            bj[BUF][0] = *(const uint2v*)(pj);                              \
            bi[BUF][0] = *(const uint2v*)(pi);                              \
            bj[BUF][1] = *(const uint2v*)(pj + 64);                         \
            bi[BUF][1] = *(const uint2v*)(pi + 64);                         \
            bj[BUF][2] = *(const uint2v*)(pj + 128);                        \
            bi[BUF][2] = *(const uint2v*)(pi + 128);                        \
        }

        uint2v bj[3][3], bi[3][3];
        GLD(0, sidx[node][0], sidx[node][16]);
        GLD(1, sidx[node][1], sidx[node][17]);

        float m[3][4];
#pragma unroll
        for (int t = 0; t < 3; t++)
#pragma unroll
            for (int c = 0; c < 4; c++) m[t][c] = -INFINITY;

#pragma unroll
        for (int k = 0; k < K_; k++) {
            int cb = k % 3;
            if (k + 2 < K_) {
                int pb = (k + 2) % 3;
                GLD(pb, sidx[node][k + 2], sidx[node][16 + k + 2]);
            }
#pragma unroll
            for (int t = 0; t < 3; t++) {
                uint2v vj = bj[cb][t], vi = bi[cb][t];
                m[t][0] = fmaxf(m[t][0], bf_lo(vj.x) - bf_lo(vi.x));
                m[t][1] = fmaxf(m[t][1], bf_hi(vj.x) - bf_hi(vi.x));
                m[t][2] = fmaxf(m[t][2], bf_lo(vj.y) - bf_lo(vi.y));
                m[t][3] = fmaxf(m[t][3], bf_hi(vj.y) - bf_hi(vi.y));
            }
        }
#undef GLD

#pragma unroll
        for (int t = 0; t < 3; t++) {
            short4v s;
            s.x = (short)f2bf(m[t][0]);
            s.y = (short)f2bf(m[t][1]);
            s.z = (short)f2bf(m[t][2]);
            s.w = (short)f2bf(m[t][3]);
            *(short4v*)&ytile[node][C_ + t * 64 + l4 * 4] = s;
        }
    }
    __syncthreads();

    // ---- GEMM: wave w -> o rows [w*48, w*48+48), n = 16 local nodes ----
    int m16  = lane & 15;
    int quad = lane >> 4;
    const unsigned short* wbase = Wb + (size_t)(wave * 48 + m16) * TWOC_ + quad * 8;

    floatx4 acc[3];
#pragma unroll
    for (int i = 0; i < 3; i++) acc[i] = (floatx4){0.f, 0.f, 0.f, 0.f};

#pragma unroll
    for (int kt = 0; kt < 12; kt++) {
        short8 yf = *(const short8*)&ytile[m16][kt * 32 + quad * 8];
#pragma unroll
        for (int i = 0; i < 3; i++) {
            short8 wf = *(const short8*)(wbase + (size_t)(i * 16) * TWOC_ + kt * 32);
            acc[i] = __builtin_amdgcn_mfma_f32_16x16x32_bf16(wf, yf, acc[i], 0, 0, 0);
        }
    }

#pragma unroll
    for (int i = 0; i < 3; i++) {
#pragma unroll
        for (int r = 0; r < 4; r++) {
            int o = wave * 48 + i * 16 + quad * 4 + r;
            out[((size_t)b * O_ + o) * N_ + n0 + m16] = fmaxf(acc[i][r] + bias[o], 0.f);
        }
    }
}

extern "C" void kernel_launch(void* const* d_in, const int* in_sizes, int n_in,
                              void* d_out, int out_size, void* d_ws, size_t ws_size,
                              hipStream_t stream) {
    const float* x    = (const float*)d_in[0];
    const int*   eidx = (const int*)d_in[2];
    const float* W    = (const float*)d_in[3];
    const float* bias = (const float*)d_in[4];
    float*       out  = (float*)d_out;

    unsigned short* Wb = (unsigned short*)d_ws;                     // 147456 B
    unsigned short* xt = (unsigned short*)((char*)d_ws + 147456);   // 12.6 MB

    k_prep<<<dim3(6144 + 288), dim3(256), 0, stream>>>(x, W, xt, Wb);
    k_fused<<<dim3(2048), dim3(256), 0, stream>>>(xt, eidx, Wb, bias, out);
}

// Round 7
// 141.197 us; speedup vs baseline: 1.5823x; 1.5823x over previous
//
#include <hip/hip_runtime.h>

#define B_    4
#define C_    192
#define N_    8192
#define K_    16
#define O_    192
#define TWOC_ 384
#define YPAD  392   // LDS row stride (shorts): 196 dwords = 4 mod 32 banks -> 2-way (free)

typedef __attribute__((ext_vector_type(8))) short short8;
typedef __attribute__((ext_vector_type(4))) short short4v;
typedef __attribute__((ext_vector_type(2))) unsigned int uint2v;
typedef __attribute__((ext_vector_type(4))) float floatx4;

static __device__ __forceinline__ float bf_lo(unsigned int u) {
    union { unsigned int i; float f; } v; v.i = u << 16; return v.f;
}
static __device__ __forceinline__ float bf_hi(unsigned int u) {
    union { unsigned int i; float f; } v; v.i = u & 0xffff0000u; return v.f;
}
static __device__ __forceinline__ unsigned short f2bf(float f) {
    union { float f; unsigned int i; } v; v.f = f;
    unsigned int x = v.i;
    return (unsigned short)((x + 0x7FFFu + ((x >> 16) & 1u)) >> 16);
}

// ---------------- K0: transpose x[B,C,N] fp32 -> xt[B,N,192] bf16 ; tail = W->bf16 ----------------
__global__ __launch_bounds__(256) void k_prep(const float* __restrict__ x,
                                              const float* __restrict__ W,
                                              unsigned short* __restrict__ xt,
                                              unsigned short* __restrict__ Wb) {
    int bid = blockIdx.x;
    if (bid >= 6144) {                   // 288 tail blocks: W fp32 -> bf16
        int i = (bid - 6144) * 256 + threadIdx.x;
        if (i < O_ * TWOC_) Wb[i] = f2bf(W[i]);
        return;
    }
    __shared__ float tile[32][33];
    int xcd  = bid & 7;
    int b    = xcd >> 1;
    int half = xcd & 1;
    int slot = bid >> 3;                 // 0..767
    int ct   = slot >> 7;                // 0..5
    int nt   = half * 128 + (slot & 127);
    int c0 = ct * 32, n0 = nt * 32;
    int tid = threadIdx.x;

    int cc  = tid >> 3;
    int nn4 = (tid & 7) * 4;
    const float* xp = x + ((size_t)b * C_ + c0 + cc) * N_ + n0 + nn4;
    float4 v = *(const float4*)xp;
    tile[nn4 + 0][cc] = v.x;
    tile[nn4 + 1][cc] = v.y;
    tile[nn4 + 2][cc] = v.z;
    tile[nn4 + 3][cc] = v.w;
    __syncthreads();

#pragma unroll
    for (int i = 0; i < 2; i++) {
        int id  = i * 256 + tid;
        int row = id >> 4;
        int ch2 = id & 15;
        float a = tile[row][ch2 * 2];
        float c = tile[row][ch2 * 2 + 1];
        unsigned int pack = (unsigned int)f2bf(a) | ((unsigned int)f2bf(c) << 16);
        *(unsigned int*)(xt + ((size_t)b * N_ + n0 + row) * C_ + c0 + ch2 * 2) = pack;
    }
}

// ---------------- K1: fused max-rel gather + 1x1 conv (MFMA), 32 nodes/block ----------------
// R3 structure (measured 49.6 us) + nontemporal out stores / eidx loads to keep
// xt L2-resident (gathers are MSHR-capped: time = lines/CU * latency / ~24;
// the only movable term here is latency via L2 hit rate).
__global__ __launch_bounds__(256, 4) void k_fused(const unsigned short* __restrict__ xt,
                                                  const int* __restrict__ eidx,
                                                  const unsigned short* __restrict__ Wb,
                                                  const float* __restrict__ bias,
                                                  float* __restrict__ out) {
    __shared__ unsigned short ytile[32][YPAD];    // 24.5 KiB
    __shared__ int sidx[32][33];                  // 4.1 KiB

    int bid  = blockIdx.x;               // 1024 blocks
    int xcd  = bid & 7;
    int b    = xcd >> 1;
    int slot = bid >> 3;                 // 0..127
    int n0   = ((xcd & 1) * 128 + slot) * 32;

    int tid  = threadIdx.x;
    int wave = tid >> 6;
    int lane = tid & 63;

    // ---- edge indices (nontemporal stream): sidx[node][0..15]=j, [16..31]=i ----
    {
        const int* e0 = eidx + ((size_t)b * N_ + n0) * K_;
        const int* e1 = e0 + (size_t)B_ * N_ * K_;
#pragma unroll
        for (int i = 0; i < 2; i++) {
            int id = i * 256 + tid;      // 0..511
            int node = id >> 4, k = id & 15;
            sidx[node][k]      = __builtin_nontemporal_load(e0 + id);
            sidx[node][16 + k] = __builtin_nontemporal_load(e1 + id);
        }
    }

    // ---- stage A: own xs rows -> ytile[:, 0..191] ----
    {
        const unsigned short* xrow = xt + ((size_t)b * N_ + n0) * C_;
#pragma unroll
        for (int i = 0; i < 3; i++) {
            int id = i * 256 + tid;      // 0..767
            int row = id / 24, chunk = id % 24;
            short8 v = *(const short8*)(xrow + (size_t)row * C_ + chunk * 8);
            *(short8*)&ytile[row][chunk * 8] = v;
        }
    }
    __syncthreads();

    // ---- stage B: gather max-rel -> ytile[:, 192..383] ----
    {
        int g  = lane >> 4;
        int l4 = lane & 15;
        const unsigned short* xbase = xt + (size_t)b * N_ * C_;

#define GLD(BUF, JN, IN)                                                    \
        {                                                                   \
            const unsigned short* pj = xbase + (size_t)(JN) * C_ + l4 * 4;  \
            const unsigned short* pi = xbase + (size_t)(IN) * C_ + l4 * 4;  \
            bj[BUF][0] = *(const uint2v*)(pj);                              \
            bi[BUF][0] = *(const uint2v*)(pi);                              \
            bj[BUF][1] = *(const uint2v*)(pj + 64);                         \
            bi[BUF][1] = *(const uint2v*)(pi + 64);                         \
            bj[BUF][2] = *(const uint2v*)(pj + 128);                        \
            bi[BUF][2] = *(const uint2v*)(pi + 128);                        \
        }

#pragma unroll
        for (int bb = 0; bb < 2; bb++) {
            int node = wave * 8 + bb * 4 + g;

            uint2v bj[2][3], bi[2][3];
            GLD(0, sidx[node][0], sidx[node][16]);

            float m[3][4];
#pragma unroll
            for (int t = 0; t < 3; t++)
#pragma unroll
                for (int c = 0; c < 4; c++) m[t][c] = -INFINITY;

#pragma unroll
            for (int k = 0; k < K_; k++) {
                int cb = k & 1, nb = cb ^ 1;
                if (k + 1 < K_) {
                    GLD(nb, sidx[node][k + 1], sidx[node][16 + k + 1]);
                }
#pragma unroll
                for (int t = 0; t < 3; t++) {
                    uint2v vj = bj[cb][t], vi = bi[cb][t];
                    m[t][0] = fmaxf(m[t][0], bf_lo(vj.x) - bf_lo(vi.x));
                    m[t][1] = fmaxf(m[t][1], bf_hi(vj.x) - bf_hi(vi.x));
                    m[t][2] = fmaxf(m[t][2], bf_lo(vj.y) - bf_lo(vi.y));
                    m[t][3] = fmaxf(m[t][3], bf_hi(vj.y) - bf_hi(vi.y));
                }
            }
#undef GLD

#pragma unroll
            for (int t = 0; t < 3; t++) {
                short4v s;
                s.x = (short)f2bf(m[t][0]);
                s.y = (short)f2bf(m[t][1]);
                s.z = (short)f2bf(m[t][2]);
                s.w = (short)f2bf(m[t][3]);
                *(short4v*)&ytile[node][C_ + t * 64 + l4 * 4] = s;
            }
        }
    }
    __syncthreads();

    // ---- GEMM: wave w -> o rows [w*48, w*48+48), n = 32 local nodes ----
    int m16  = lane & 15;
    int quad = lane >> 4;
    const unsigned short* wbase = Wb + (size_t)(wave * 48 + m16) * TWOC_ + quad * 8;

    floatx4 acc[3][2];
#pragma unroll
    for (int i = 0; i < 3; i++)
#pragma unroll
        for (int j = 0; j < 2; j++) acc[i][j] = (floatx4){0.f, 0.f, 0.f, 0.f};

#pragma unroll
    for (int kt = 0; kt < 12; kt++) {
        short8 wf[3], yf[2];
#pragma unroll
        for (int i = 0; i < 3; i++)
            wf[i] = *(const short8*)(wbase + (size_t)(i * 16) * TWOC_ + kt * 32);
#pragma unroll
        for (int j = 0; j < 2; j++)
            yf[j] = *(const short8*)&ytile[j * 16 + m16][kt * 32 + quad * 8];
#pragma unroll
        for (int i = 0; i < 3; i++)
#pragma unroll
            for (int j = 0; j < 2; j++)
                acc[i][j] = __builtin_amdgcn_mfma_f32_16x16x32_bf16(wf[i], yf[j], acc[i][j], 0, 0, 0);
    }

#pragma unroll
    for (int i = 0; i < 3; i++) {
#pragma unroll
        for (int r = 0; r < 4; r++) {
            int o = wave * 48 + i * 16 + quad * 4 + r;
            float bv = bias[o];
#pragma unroll
            for (int j = 0; j < 2; j++) {
                int n = n0 + j * 16 + m16;
                __builtin_nontemporal_store(fmaxf(acc[i][j][r] + bv, 0.f),
                                            out + ((size_t)b * O_ + o) * N_ + n);
            }
        }
    }
}

extern "C" void kernel_launch(void* const* d_in, const int* in_sizes, int n_in,
                              void* d_out, int out_size, void* d_ws, size_t ws_size,
                              hipStream_t stream) {
    const float* x    = (const float*)d_in[0];
    const int*   eidx = (const int*)d_in[2];
    const float* W    = (const float*)d_in[3];
    const float* bias = (const float*)d_in[4];
    float*       out  = (float*)d_out;

    unsigned short* Wb = (unsigned short*)d_ws;                     // 147456 B
    unsigned short* xt = (unsigned short*)((char*)d_ws + 147456);   // 12.6 MB

    k_prep<<<dim3(6144 + 288), dim3(256), 0, stream>>>(x, W, xt, Wb);
    k_fused<<<dim3(1024), dim3(256), 0, stream>>>(xt, eidx, Wb, bias, out);
}